// Round 10
// baseline (1493.869 us; speedup 1.0000x reference)
//
#include <hip/hip_runtime.h>
#include <hip/hip_bf16.h>
#include <math.h>

#define EPS 1e-5f

typedef __attribute__((ext_vector_type(8))) short bf16x8;
typedef __attribute__((ext_vector_type(4))) float f32x4;

__device__ inline ushort f2bf(float f) {
    uint u = __float_as_uint(f);
    uint r = (u + 0x7fffu + ((u >> 16) & 1u)) >> 16;
    return (ushort)r;
}
__device__ inline float bf2f(ushort u) {
    return __uint_as_float(((uint)u) << 16);
}
__device__ inline float sigmoidf_(float x) { return 1.f / (1.f + expf(-x)); }

__device__ inline void gload16(const void* g, void* l) {
    __builtin_amdgcn_global_load_lds((const __attribute__((address_space(1))) unsigned int*)g,
                                     (__attribute__((address_space(3))) unsigned int*)l,
                                     16, 0, 0);
}

// ---------------------------------------------------------------------------
// Attention head (single block, 256 threads). B=16, A=16, K=4 fixed.
// ---------------------------------------------------------------------------
__global__ void attn_kernel(const float* __restrict__ pooled,
                            const float* __restrict__ fc_w,
                            const float* __restrict__ bn_g, const float* __restrict__ bn_b,
                            const float* __restrict__ ch_w, const float* __restrict__ ch_b,
                            const float* __restrict__ fl_w, const float* __restrict__ fl_b,
                            const float* __restrict__ sp_w, const float* __restrict__ sp_b,
                            const float* __restrict__ kn_w, const float* __restrict__ kn_b,
                            float* __restrict__ ch_att, float* __restrict__ fl_att,
                            float* __restrict__ sp_att, float* __restrict__ kn_att,
                            int C, int Cout) {
    const int Bb = 16, A = 16, K = 4;
    __shared__ float h[16][16];
    int tid = threadIdx.x;

    if (tid < Bb * A) {
        int b = tid >> 4, a = tid & 15;
        const float* pr = pooled + b * C;
        const float* fw = fc_w + a * C;
        float s = 0.f;
        for (int c = 0; c < C; c++) s += pr[c] * fw[c];
        h[b][a] = s;
    }
    __syncthreads();

    if (tid < A) {
        int a = tid;
        float m = 0.f;
        for (int b = 0; b < Bb; b++) m += h[b][a];
        m *= (1.f / 16.f);
        float v = 0.f;
        for (int b = 0; b < Bb; b++) { float d = h[b][a] - m; v += d * d; }
        v *= (1.f / 16.f);
        float inv = rsqrtf(v + EPS);
        float g = bn_g[a], bb = bn_b[a];
        for (int b = 0; b < Bb; b++) {
            float t = (h[b][a] - m) * inv * g + bb;
            h[b][a] = t > 0.f ? t : 0.f;
        }
    }
    __syncthreads();

    for (int idx = tid; idx < Bb * C; idx += blockDim.x) {
        int b = idx / C, c = idx % C;
        float s = ch_b[c];
        #pragma unroll
        for (int a = 0; a < A; a++) s += h[b][a] * ch_w[c * A + a];
        ch_att[idx] = sigmoidf_(s);
    }
    for (int idx = tid; idx < Bb * Cout; idx += blockDim.x) {
        int b = idx / Cout, o = idx % Cout;
        float s = fl_b[o];
        #pragma unroll
        for (int a = 0; a < A; a++) s += h[b][a] * fl_w[o * A + a];
        fl_att[idx] = sigmoidf_(s);
    }
    for (int idx = tid; idx < Bb * 9; idx += blockDim.x) {
        int b = idx / 9, r = idx % 9;
        float s = sp_b[r];
        #pragma unroll
        for (int a = 0; a < A; a++) s += h[b][a] * sp_w[r * A + a];
        sp_att[idx] = sigmoidf_(s);
    }
    if (tid < Bb) {
        int b = tid;
        float l[K], mx = -1e30f;
        #pragma unroll
        for (int k = 0; k < K; k++) {
            float s = kn_b[k];
            #pragma unroll
            for (int a = 0; a < A; a++) s += h[b][a] * kn_w[k * A + a];
            l[k] = s; mx = fmaxf(mx, s);
        }
        float den = 0.f;
        #pragma unroll
        for (int k = 0; k < K; k++) { l[k] = expf(l[k] - mx); den += l[k]; }
        #pragma unroll
        for (int k = 0; k < K; k++) kn_att[b * K + k] = l[k] / den;
    }
}

// ---------------------------------------------------------------------------
// Effective weight aggregation -> bf16 in 16x16x32 MFMA A-fragment order.
// WbF[(((b*NT + t)*8 + ot)*64 + lane)*8 + e]: o=ot*16+(lane&15),
// k=t*32+(lane>>4)*8+e, k=rs*Cin+i.
// ---------------------------------------------------------------------------
__global__ void waggF_kernel(const float* __restrict__ W4, const float* __restrict__ ch,
                             const float* __restrict__ fl, const float* __restrict__ sp,
                             const float* __restrict__ kn, ushort* __restrict__ WbF,
                             int Cout, int Cin, int NT, int N) {
    int idx = blockIdx.x * blockDim.x + threadIdx.x;
    if (idx >= N) return;
    int e = idx & 7;
    int l = (idx >> 3) & 63;
    int ot = (idx >> 9) & 7;
    int tb = idx >> 12;
    int t = tb % NT, b = tb / NT;
    int o = ot * 16 + (l & 15);
    int k = t * 32 + ((l >> 4) << 3) + e;
    int rs = k / Cin, i = k - rs * Cin;
    size_t kstride = (size_t)Cout * Cin * 9;
    const float* wp = W4 + ((size_t)o * Cin + i) * 9 + rs;
    const float* kp = kn + b * 4;
    float s = kp[0] * wp[0] + kp[1] * wp[kstride] + kp[2] * wp[2 * kstride] + kp[3] * wp[3 * kstride];
    float v = fl[b * Cout + o] * ch[b * Cin + i] * sp[b * 9 + rs] * s;
    WbF[idx] = f2bf(v);
}

// ---------------------------------------------------------------------------
// NCHW (fp32 OR bf16) -> NHWC bf16 tiled transpose, optional BN+ReLU, fused
// global-avg-pool partials. grid ((C/32)*(W/32), H, B), block 256.
// ---------------------------------------------------------------------------
__global__ __launch_bounds__(256) void trans_kernel(const float* __restrict__ in32,
                                                    const ushort* __restrict__ in16,
                                                    ushort* __restrict__ out,
                                                    float* __restrict__ ppart,
                                                    const float* __restrict__ stats,
                                                    const float* __restrict__ g,
                                                    const float* __restrict__ beta,
                                                    int C, int doBN) {
    int tilesC = C >> 5;
    int cbi = blockIdx.x % tilesC;
    int pbi = blockIdx.x / tilesC;
    int cb = cbi << 5, pb = pbi << 5;
    int y = blockIdx.y, b = blockIdx.z;
    __shared__ float tile[32][33];
    int t = threadIdx.x;
    int p = t & 31, c0 = t >> 5;
    float vj[4];
    #pragma unroll
    for (int j = 0; j < 4; j++) {
        int cl = c0 + j * 8;
        int c = cb + cl;
        size_t idx = (((size_t)b * C + c) * 128 + y) * 128 + pb + p;
        float v = in16 ? bf2f(in16[idx]) : in32[idx];
        if (doBN) {
            v = (v - stats[2 * c]) * stats[2 * c + 1] * g[c] + beta[c];
            v = fmaxf(v, 0.f);
        }
        tile[cl][p] = v;
        vj[j] = v;
    }
    #pragma unroll
    for (int j = 0; j < 4; j++) {
        float s = vj[j];
        #pragma unroll
        for (int msk = 1; msk < 32; msk <<= 1) s += __shfl_xor(s, msk);
        if (p == 0) {
            int cl = c0 + j * 8;
            ppart[((size_t)((b * tilesC + cbi) * 32 + cl)) * 512 + pbi * 128 + y] = s;
        }
    }
    __syncthreads();
    int c2 = (t & 15) << 1, pp = t >> 4;
    #pragma unroll
    for (int j = 0; j < 2; j++) {
        int p2 = pp + j * 16;
        uint lo = f2bf(tile[c2][p2]);
        uint hi = f2bf(tile[c2 + 1][p2]);
        *(uint*)&out[(((size_t)b * 128 + y) * 128 + pb + p2) * C + cb + c2] = lo | (hi << 16);
    }
}

// ---------------------------------------------------------------------------
// Reduce pool partials. grid=B*C.
// ---------------------------------------------------------------------------
__global__ void poolred_kernel(const float* __restrict__ part, float* __restrict__ pool) {
    int bc = blockIdx.x;
    const float* p = part + (size_t)bc * 512;
    float s = 0.f;
    for (int i = threadIdx.x; i < 512; i += 128) s += p[i];
    #pragma unroll
    for (int off = 32; off; off >>= 1) s += __shfl_down(s, off);
    __shared__ float tmp[2];
    if ((threadIdx.x & 63) == 0) tmp[threadIdx.x >> 6] = s;
    __syncthreads();
    if (!threadIdx.x) pool[bc] = (tmp[0] + tmp[1]) * (1.f / 16384.f);
}

// ---------------------------------------------------------------------------
// Implicit-GEMM conv 3x3 pad 1 via MFMA 16x16x32. Round-6 inner indexing
// (verified), SINGLE-buffer LDS (~27 KB) -> 6 blocks/CU inter-block overlap.
// 256 threads / 4 waves, block = (b,y): 128 oc x 128 px. Grid 2048 with XCD
// swizzle. 32-ch chunks staged via global_load_lds, source-side XOR swizzle.
// Fused BN partial stats. Output bf16 or fp32 NCHW.
// ---------------------------------------------------------------------------
__global__ __launch_bounds__(256, 6) void conv_mfma(const ushort* __restrict__ xT,
                                                    const ushort* __restrict__ WbF,
                                                    float* __restrict__ outF,
                                                    ushort* __restrict__ out16,
                                                    float* __restrict__ part,
                                                    int Cin, int use16) {
    const int BUFSH = 3 * 130 * 32;              // 12,480 shorts = 24,960 B
    __shared__ short sx[BUFSH];
    __shared__ float sred[4][64][2];
    int id = blockIdx.x;
    int swz = (id & 7) * (gridDim.x >> 3) + (id >> 3);
    int y = swz & 127, b = swz >> 7;
    int tid = threadIdx.x;
    int lane = tid & 63, wid = tid >> 6;
    int wm = wid >> 1, wn = wid & 1;
    int Cdiv32 = Cin >> 5;
    int NC = Cdiv32;
    int NT = 9 * Cdiv32;

    f32x4 acc[4][4] = {};

    // zero buffer once: halo pixels (P=0,129) and OOB rows stay zero forever
    {
        bf16x8 z = {};
        for (int e = tid * 8; e < BUFSH; e += 2048) *(bf16x8*)&sx[e] = z;
    }
    __syncthreads();

    const size_t rowstride = (size_t)128 * Cin;

    auto stage = [&](int ck) {
        #pragma unroll
        for (int j = 0; j < 6; j++) {
            int cc = wid + 4 * j;                 // 24 wave-calls: 3 rows x 8
            int r = cc >> 3, q = cc & 7;
            int yy = y + r - 1;
            if ((unsigned)yy < 128u) {
                int u = (q << 6) + lane;
                int P = (u >> 2) + 1;             // pixel slot 1..128
                int slog = (u & 3) ^ ((P >> 1) & 3);
                const ushort* gp = xT + (size_t)(b * 128 + yy) * rowstride
                                      + (size_t)(P - 1) * Cin + (ck << 5) + (slog << 3);
                short* lp = &sx[(r * 130 + 1) * 32 + (q << 9)];
                gload16(gp, lp);
            }
        }
    };

    const bf16x8* Ab = (const bf16x8*)WbF;
    size_t abase = (size_t)b * NT;

    for (int ck = 0; ck < NC; ck++) {
        stage(ck);
        __syncthreads();                          // drains vmcnt, data visible
        #pragma unroll 3
        for (int rs = 0; rs < 9; rs++) {
            int rr = (rs / 3) * 130;
            int dx = rs % 3 - 1;
            int t = rs * Cdiv32 + ck;
            bf16x8 a[4], bv[4];
            size_t ai = ((abase + t) * 8 + wm * 4) * 64 + lane;
            #pragma unroll
            for (int m = 0; m < 4; m++) a[m] = Ab[ai + (size_t)m * 64];
            int Pb = wn * 64 + (lane & 15) + dx + 1;
            int slog = lane >> 4;
            #pragma unroll
            for (int n = 0; n < 4; n++) {
                int P = Pb + n * 16;
                bv[n] = *(const bf16x8*)&sx[(rr + P) * 32 + ((slog ^ ((P >> 1) & 3)) << 3)];
            }
            #pragma unroll
            for (int m = 0; m < 4; m++)
                #pragma unroll
                for (int n = 0; n < 4; n++)
                    acc[m][n] = __builtin_amdgcn_mfma_f32_16x16x32_bf16(
                        a[m], bv[n], acc[m][n], 0, 0, 0);
        }
        if (ck + 1 < NC) __syncthreads();         // protect buffer before restage
    }

    // epilogue: D row=(lane>>4)*4+r -> out channel, col=lane&15 -> pixel
    int px = wn * 64 + (lane & 15);
    int orow0 = wm * 64 + ((lane >> 4) << 2);
    if (use16) {
        #pragma unroll
        for (int m = 0; m < 4; m++)
            #pragma unroll
            for (int r = 0; r < 4; r++) {
                int oc = orow0 + m * 16 + r;
                ushort* po = out16 + ((size_t)(b * 128 + oc) * 128 + y) * 128 + px;
                #pragma unroll
                for (int n = 0; n < 4; n++) po[n * 16] = f2bf(acc[m][n][r]);
            }
    } else {
        #pragma unroll
        for (int m = 0; m < 4; m++)
            #pragma unroll
            for (int r = 0; r < 4; r++) {
                int oc = orow0 + m * 16 + r;
                float* po = outF + ((size_t)(b * 128 + oc) * 128 + y) * 128 + px;
                #pragma unroll
                for (int n = 0; n < 4; n++) po[n * 16] = acc[m][n][r];
            }
    }

    // fused per-channel partial stats (exact fp32 accumulators)
    #pragma unroll
    for (int m = 0; m < 4; m++)
        #pragma unroll
        for (int r = 0; r < 4; r++) {
            float s = 0.f, q = 0.f;
            #pragma unroll
            for (int n = 0; n < 4; n++) { float v = acc[m][n][r]; s += v; q += v * v; }
            #pragma unroll
            for (int msk = 1; msk < 16; msk <<= 1) {
                s += __shfl_xor(s, msk);
                q += __shfl_xor(q, msk);
            }
            if ((lane & 15) == 0) {
                int chl = m * 16 + ((lane >> 4) << 2) + r;
                sred[wid][chl][0] = s;
                sred[wid][chl][1] = q;
            }
        }
    __syncthreads();
    {
        int ch = tid >> 1, v = tid & 1;
        int wmc = ch >> 6, chl = ch & 63;
        float t2 = sred[wmc * 2][chl][v] + sred[wmc * 2 + 1][chl][v];
        part[((size_t)(b * 128 + y)) * 256 + tid] = t2;
    }
}

// ---------------------------------------------------------------------------
// Reduce per-block partials -> per-channel mean + invstd. grid = 128.
// ---------------------------------------------------------------------------
__global__ void bnred_kernel(const float* __restrict__ part, float* __restrict__ stats,
                             int nrows) {
    int c = blockIdx.x;
    float s = 0.f, q = 0.f;
    for (int by = threadIdx.x; by < nrows; by += blockDim.x) {
        s += part[(size_t)by * 256 + 2 * c];
        q += part[(size_t)by * 256 + 2 * c + 1];
    }
    #pragma unroll
    for (int off = 32; off; off >>= 1) { s += __shfl_down(s, off); q += __shfl_down(q, off); }
    __shared__ float ss[4], qq[4];
    int lane = threadIdx.x & 63, w = threadIdx.x >> 6;
    if (!lane) { ss[w] = s; qq[w] = q; }
    __syncthreads();
    if (!threadIdx.x) {
        s = ss[0] + ss[1] + ss[2] + ss[3];
        q = qq[0] + qq[1] + qq[2] + qq[3];
        const float n = 16.f * 16384.f;
        float m = s / n;
        float var = q / n - m * m;
        stats[2 * c] = m;
        stats[2 * c + 1] = rsqrtf(var + EPS);
    }
}

// ---------------------------------------------------------------------------
// BN apply + ReLU, fp32 NCHW in place.
// ---------------------------------------------------------------------------
__global__ void bnapply_kernel(float4* __restrict__ buf, const float* __restrict__ stats,
                               const float* __restrict__ g, const float* __restrict__ bta,
                               size_t N4) {
    size_t idx = (size_t)blockIdx.x * blockDim.x + threadIdx.x;
    size_t stride = (size_t)gridDim.x * blockDim.x;
    for (; idx < N4; idx += stride) {
        int c = (int)((idx >> 12) & 127);
        float sc = stats[2 * c + 1] * g[c];
        float sh = bta[c] - stats[2 * c] * sc;
        float4 v = buf[idx];
        v.x = fmaxf(v.x * sc + sh, 0.f);
        v.y = fmaxf(v.y * sc + sh, 0.f);
        v.z = fmaxf(v.z * sc + sh, 0.f);
        v.w = fmaxf(v.w * sc + sh, 0.f);
        buf[idx] = v;
    }
}

// ---------------------------------------------------------------------------
// BN apply + ReLU: bf16 NCHW in -> fp32 NCHW out.
// ---------------------------------------------------------------------------
__global__ void bnapply16_kernel(const ushort* __restrict__ in, float4* __restrict__ out,
                                 const float* __restrict__ stats,
                                 const float* __restrict__ g, const float* __restrict__ bta,
                                 size_t N4) {
    size_t idx = (size_t)blockIdx.x * blockDim.x + threadIdx.x;
    size_t stride = (size_t)gridDim.x * blockDim.x;
    for (; idx < N4; idx += stride) {
        int c = (int)((idx >> 12) & 127);
        float sc = stats[2 * c + 1] * g[c];
        float sh = bta[c] - stats[2 * c] * sc;
        ushort4 u = *(const ushort4*)&in[idx * 4];
        float4 v;
        v.x = fmaxf(bf2f(u.x) * sc + sh, 0.f);
        v.y = fmaxf(bf2f(u.y) * sc + sh, 0.f);
        v.z = fmaxf(bf2f(u.z) * sc + sh, 0.f);
        v.w = fmaxf(bf2f(u.w) * sc + sh, 0.f);
        out[idx] = v;
    }
}

// ---------------------------------------------------------------------------
extern "C" void kernel_launch(void* const* d_in, const int* in_sizes, int n_in,
                              void* d_out, int out_size, void* d_ws, size_t ws_size,
                              hipStream_t stream) {
    const int B = 16, Cin1 = 64, C = 128, H = 128, W = 128, HW = H * W;

    const float* x      = (const float*)d_in[0];
    const float* w1     = (const float*)d_in[1];
    const float* a_fc_w = (const float*)d_in[2];
    const float* a_bn_g = (const float*)d_in[3];
    const float* a_bn_b = (const float*)d_in[4];
    const float* a_ch_w = (const float*)d_in[5];
    const float* a_ch_b = (const float*)d_in[6];
    const float* a_fl_w = (const float*)d_in[7];
    const float* a_fl_b = (const float*)d_in[8];
    const float* a_sp_w = (const float*)d_in[9];
    const float* a_sp_b = (const float*)d_in[10];
    const float* a_kn_w = (const float*)d_in[11];
    const float* a_kn_b = (const float*)d_in[12];
    const float* bn1_g  = (const float*)d_in[13];
    const float* bn1_b  = (const float*)d_in[14];
    const float* w2     = (const float*)d_in[15];
    const float* b_fc_w = (const float*)d_in[16];
    const float* b_bn_g = (const float*)d_in[17];
    const float* b_bn_b = (const float*)d_in[18];
    const float* b_ch_w = (const float*)d_in[19];
    const float* b_ch_b = (const float*)d_in[20];
    const float* b_fl_w = (const float*)d_in[21];
    const float* b_fl_b = (const float*)d_in[22];
    const float* b_sp_w = (const float*)d_in[23];
    const float* b_sp_b = (const float*)d_in[24];
    const float* b_kn_w = (const float*)d_in[25];
    const float* b_kn_b = (const float*)d_in[26];
    const float* bn2_g  = (const float*)d_in[27];
    const float* bn2_b  = (const float*)d_in[28];

    float* out = (float*)d_out;
    float* ws  = (float*)d_ws;

    // workspace layout (floats)
    float* XTf   = ws;
    ushort* xT   = (ushort*)XTf;
    float* WBf   = XTf + 16777216;
    ushort* WbF  = (ushort*)WBf;
    float* CPART = WBf + 1179648;
    float* PPART = CPART + 524288;
    float* POOL  = PPART + 1048576;
    float* CH    = POOL + 2048;
    float* FL    = CH + 2048;
    float* SP    = FL + 2048;
    float* KN    = SP + 160;
    float* ST    = KN + 64;
    float* XH2f  = ST + 256;
    ushort* xhat2 = (ushort*)XH2f;

    size_t need = ((size_t)(XH2f - ws) + 16777216) * sizeof(float);
    int fit2 = ws_size >= need;

    ushort* xhat1 = (ushort*)out;                    // d_out as bf16 NCHW scratch

    // ---------------- layer 1 (Cin=64 -> Cout=128) ----------------
    trans_kernel<<<dim3((Cin1 / 32) * 4, H, B), 256, 0, stream>>>(
        x, nullptr, xT, PPART, ST, nullptr, nullptr, Cin1, 0);
    poolred_kernel<<<B * Cin1, 128, 0, stream>>>(PPART, POOL);
    attn_kernel<<<1, 256, 0, stream>>>(POOL, a_fc_w, a_bn_g, a_bn_b, a_ch_w, a_ch_b,
                                       a_fl_w, a_fl_b, a_sp_w, a_sp_b, a_kn_w, a_kn_b,
                                       CH, FL, SP, KN, Cin1, C);
    int NT1 = 9 * Cin1 / 32;
    int N1 = B * NT1 * 4096;
    waggF_kernel<<<(N1 + 255) / 256, 256, 0, stream>>>(w1, CH, FL, SP, KN, WbF, C, Cin1, NT1, N1);
    conv_mfma<<<H * B, 256, 0, stream>>>(xT, WbF, nullptr, xhat1, CPART, Cin1, 1);
    bnred_kernel<<<C, 256, 0, stream>>>(CPART, ST, 2048);
    trans_kernel<<<dim3((C / 32) * 4, H, B), 256, 0, stream>>>(
        nullptr, xhat1, xT, PPART, ST, bn1_g, bn1_b, C, 1);

    // ---------------- layer 2 (Cin=128 -> Cout=128) ----------------
    poolred_kernel<<<B * C, 128, 0, stream>>>(PPART, POOL);
    attn_kernel<<<1, 256, 0, stream>>>(POOL, b_fc_w, b_bn_g, b_bn_b, b_ch_w, b_ch_b,
                                       b_fl_w, b_fl_b, b_sp_w, b_sp_b, b_kn_w, b_kn_b,
                                       CH, FL, SP, KN, C, C);
    int NT2 = 9 * C / 32;
    int N2 = B * NT2 * 4096;
    waggF_kernel<<<(N2 + 255) / 256, 256, 0, stream>>>(w2, CH, FL, SP, KN, WbF, C, C, NT2, N2);
    if (fit2) {
        conv_mfma<<<H * B, 256, 0, stream>>>(xT, WbF, nullptr, xhat2, CPART, C, 1);
        bnred_kernel<<<C, 256, 0, stream>>>(CPART, ST, 2048);
        bnapply16_kernel<<<2048, 256, 0, stream>>>(xhat2, (float4*)out, ST, bn2_g, bn2_b,
                                                   (size_t)B * C * HW / 4);
    } else {
        conv_mfma<<<H * B, 256, 0, stream>>>(xT, WbF, out, nullptr, CPART, C, 0);
        bnred_kernel<<<C, 256, 0, stream>>>(CPART, ST, 2048);
        bnapply_kernel<<<2048, 256, 0, stream>>>((float4*)out, ST, bn2_g, bn2_b,
                                                 (size_t)B * C * HW / 4);
    }
}

// Round 11
// 356.573 us; speedup vs baseline: 4.1895x; 4.1895x over previous
//
#include <hip/hip_runtime.h>
#include <hip/hip_bf16.h>
#include <math.h>

#define EPS 1e-5f

typedef __attribute__((ext_vector_type(8))) short bf16x8;
typedef __attribute__((ext_vector_type(4))) float f32x4;

__device__ inline ushort f2bf(float f) {
    uint u = __float_as_uint(f);
    uint r = (u + 0x7fffu + ((u >> 16) & 1u)) >> 16;
    return (ushort)r;
}
__device__ inline float bf2f(ushort u) {
    return __uint_as_float(((uint)u) << 16);
}
__device__ inline float sigmoidf_(float x) { return 1.f / (1.f + expf(-x)); }

__device__ inline void gload16(const void* g, void* l) {
    __builtin_amdgcn_global_load_lds((const __attribute__((address_space(1))) unsigned int*)g,
                                     (__attribute__((address_space(3))) unsigned int*)l,
                                     16, 0, 0);
}

// ---------------------------------------------------------------------------
// Attention head (single block, 256 threads). B=16, A=16, K=4 fixed.
// ---------------------------------------------------------------------------
__global__ void attn_kernel(const float* __restrict__ pooled,
                            const float* __restrict__ fc_w,
                            const float* __restrict__ bn_g, const float* __restrict__ bn_b,
                            const float* __restrict__ ch_w, const float* __restrict__ ch_b,
                            const float* __restrict__ fl_w, const float* __restrict__ fl_b,
                            const float* __restrict__ sp_w, const float* __restrict__ sp_b,
                            const float* __restrict__ kn_w, const float* __restrict__ kn_b,
                            float* __restrict__ ch_att, float* __restrict__ fl_att,
                            float* __restrict__ sp_att, float* __restrict__ kn_att,
                            int C, int Cout) {
    const int Bb = 16, A = 16, K = 4;
    __shared__ float h[16][16];
    int tid = threadIdx.x;

    if (tid < Bb * A) {
        int b = tid >> 4, a = tid & 15;
        const float* pr = pooled + b * C;
        const float* fw = fc_w + a * C;
        float s = 0.f;
        for (int c = 0; c < C; c++) s += pr[c] * fw[c];
        h[b][a] = s;
    }
    __syncthreads();

    if (tid < A) {
        int a = tid;
        float m = 0.f;
        for (int b = 0; b < Bb; b++) m += h[b][a];
        m *= (1.f / 16.f);
        float v = 0.f;
        for (int b = 0; b < Bb; b++) { float d = h[b][a] - m; v += d * d; }
        v *= (1.f / 16.f);
        float inv = rsqrtf(v + EPS);
        float g = bn_g[a], bb = bn_b[a];
        for (int b = 0; b < Bb; b++) {
            float t = (h[b][a] - m) * inv * g + bb;
            h[b][a] = t > 0.f ? t : 0.f;
        }
    }
    __syncthreads();

    for (int idx = tid; idx < Bb * C; idx += blockDim.x) {
        int b = idx / C, c = idx % C;
        float s = ch_b[c];
        #pragma unroll
        for (int a = 0; a < A; a++) s += h[b][a] * ch_w[c * A + a];
        ch_att[idx] = sigmoidf_(s);
    }
    for (int idx = tid; idx < Bb * Cout; idx += blockDim.x) {
        int b = idx / Cout, o = idx % Cout;
        float s = fl_b[o];
        #pragma unroll
        for (int a = 0; a < A; a++) s += h[b][a] * fl_w[o * A + a];
        fl_att[idx] = sigmoidf_(s);
    }
    for (int idx = tid; idx < Bb * 9; idx += blockDim.x) {
        int b = idx / 9, r = idx % 9;
        float s = sp_b[r];
        #pragma unroll
        for (int a = 0; a < A; a++) s += h[b][a] * sp_w[r * A + a];
        sp_att[idx] = sigmoidf_(s);
    }
    if (tid < Bb) {
        int b = tid;
        float l[K], mx = -1e30f;
        #pragma unroll
        for (int k = 0; k < K; k++) {
            float s = kn_b[k];
            #pragma unroll
            for (int a = 0; a < A; a++) s += h[b][a] * kn_w[k * A + a];
            l[k] = s; mx = fmaxf(mx, s);
        }
        float den = 0.f;
        #pragma unroll
        for (int k = 0; k < K; k++) { l[k] = expf(l[k] - mx); den += l[k]; }
        #pragma unroll
        for (int k = 0; k < K; k++) kn_att[b * K + k] = l[k] / den;
    }
}

// ---------------------------------------------------------------------------
// Effective weight aggregation -> bf16 in 16x16x32 MFMA A-fragment order.
// WbF[(((b*NT + t)*8 + ot)*64 + lane)*8 + e]: o=ot*16+(lane&15),
// k=t*32+(lane>>4)*8+e, k=rs*Cin+i.
// ---------------------------------------------------------------------------
__global__ void waggF_kernel(const float* __restrict__ W4, const float* __restrict__ ch,
                             const float* __restrict__ fl, const float* __restrict__ sp,
                             const float* __restrict__ kn, ushort* __restrict__ WbF,
                             int Cout, int Cin, int NT, int N) {
    int idx = blockIdx.x * blockDim.x + threadIdx.x;
    if (idx >= N) return;
    int e = idx & 7;
    int l = (idx >> 3) & 63;
    int ot = (idx >> 9) & 7;
    int tb = idx >> 12;
    int t = tb % NT, b = tb / NT;
    int o = ot * 16 + (l & 15);
    int k = t * 32 + ((l >> 4) << 3) + e;
    int rs = k / Cin, i = k - rs * Cin;
    size_t kstride = (size_t)Cout * Cin * 9;
    const float* wp = W4 + ((size_t)o * Cin + i) * 9 + rs;
    const float* kp = kn + b * 4;
    float s = kp[0] * wp[0] + kp[1] * wp[kstride] + kp[2] * wp[2 * kstride] + kp[3] * wp[3 * kstride];
    float v = fl[b * Cout + o] * ch[b * Cin + i] * sp[b * 9 + rs] * s;
    WbF[idx] = f2bf(v);
}

// ---------------------------------------------------------------------------
// NCHW (fp32 OR bf16) -> NHWC bf16 tiled transpose, optional BN+ReLU, fused
// global-avg-pool partials. grid ((C/32)*(W/32), H, B), block 256.
// ---------------------------------------------------------------------------
__global__ __launch_bounds__(256) void trans_kernel(const float* __restrict__ in32,
                                                    const ushort* __restrict__ in16,
                                                    ushort* __restrict__ out,
                                                    float* __restrict__ ppart,
                                                    const float* __restrict__ stats,
                                                    const float* __restrict__ g,
                                                    const float* __restrict__ beta,
                                                    int C, int doBN) {
    int tilesC = C >> 5;
    int cbi = blockIdx.x % tilesC;
    int pbi = blockIdx.x / tilesC;
    int cb = cbi << 5, pb = pbi << 5;
    int y = blockIdx.y, b = blockIdx.z;
    __shared__ float tile[32][33];
    int t = threadIdx.x;
    int p = t & 31, c0 = t >> 5;
    float vj[4];
    #pragma unroll
    for (int j = 0; j < 4; j++) {
        int cl = c0 + j * 8;
        int c = cb + cl;
        size_t idx = (((size_t)b * C + c) * 128 + y) * 128 + pb + p;
        float v = in16 ? bf2f(in16[idx]) : in32[idx];
        if (doBN) {
            v = (v - stats[2 * c]) * stats[2 * c + 1] * g[c] + beta[c];
            v = fmaxf(v, 0.f);
        }
        tile[cl][p] = v;
        vj[j] = v;
    }
    #pragma unroll
    for (int j = 0; j < 4; j++) {
        float s = vj[j];
        #pragma unroll
        for (int msk = 1; msk < 32; msk <<= 1) s += __shfl_xor(s, msk);
        if (p == 0) {
            int cl = c0 + j * 8;
            ppart[((size_t)((b * tilesC + cbi) * 32 + cl)) * 512 + pbi * 128 + y] = s;
        }
    }
    __syncthreads();
    int c2 = (t & 15) << 1, pp = t >> 4;
    #pragma unroll
    for (int j = 0; j < 2; j++) {
        int p2 = pp + j * 16;
        uint lo = f2bf(tile[c2][p2]);
        uint hi = f2bf(tile[c2 + 1][p2]);
        *(uint*)&out[(((size_t)b * 128 + y) * 128 + pb + p2) * C + cb + c2] = lo | (hi << 16);
    }
}

// ---------------------------------------------------------------------------
// Reduce pool partials. grid=B*C.
// ---------------------------------------------------------------------------
__global__ void poolred_kernel(const float* __restrict__ part, float* __restrict__ pool) {
    int bc = blockIdx.x;
    const float* p = part + (size_t)bc * 512;
    float s = 0.f;
    for (int i = threadIdx.x; i < 512; i += 128) s += p[i];
    #pragma unroll
    for (int off = 32; off; off >>= 1) s += __shfl_down(s, off);
    __shared__ float tmp[2];
    if ((threadIdx.x & 63) == 0) tmp[threadIdx.x >> 6] = s;
    __syncthreads();
    if (!threadIdx.x) pool[bc] = (tmp[0] + tmp[1]) * (1.f / 16384.f);
}

// ---------------------------------------------------------------------------
// Implicit-GEMM conv 3x3 pad 1 via MFMA 16x16x32. Single-buffer LDS (~27 KB),
// __launch_bounds__(256,4): VGPR budget 128 (no spill; kernel needs ~70),
// LDS allows 5 blocks/CU, VGPR allows 4 -> 4 blocks/CU inter-block overlap.
// 256 threads / 4 waves, block = (b,y): 128 oc x 128 px. Grid 2048 with XCD
// swizzle. 32-ch chunks staged via global_load_lds, source-side XOR swizzle.
// Fused BN partial stats. Output bf16 or fp32 NCHW.
// ---------------------------------------------------------------------------
__global__ __launch_bounds__(256, 4) void conv_mfma(const ushort* __restrict__ xT,
                                                    const ushort* __restrict__ WbF,
                                                    float* __restrict__ outF,
                                                    ushort* __restrict__ out16,
                                                    float* __restrict__ part,
                                                    int Cin, int use16) {
    const int BUFSH = 3 * 130 * 32;              // 12,480 shorts = 24,960 B
    __shared__ short sx[BUFSH];
    __shared__ float sred[4][64][2];
    int id = blockIdx.x;
    int swz = (id & 7) * (gridDim.x >> 3) + (id >> 3);
    int y = swz & 127, b = swz >> 7;
    int tid = threadIdx.x;
    int lane = tid & 63, wid = tid >> 6;
    int wm = wid >> 1, wn = wid & 1;
    int Cdiv32 = Cin >> 5;
    int NC = Cdiv32;
    int NT = 9 * Cdiv32;

    f32x4 acc[4][4] = {};

    // zero buffer once: halo pixels (P=0,129) and OOB rows stay zero forever
    {
        bf16x8 z = {};
        for (int e = tid * 8; e < BUFSH; e += 2048) *(bf16x8*)&sx[e] = z;
    }
    __syncthreads();

    const size_t rowstride = (size_t)128 * Cin;

    auto stage = [&](int ck) {
        #pragma unroll
        for (int j = 0; j < 6; j++) {
            int cc = wid + 4 * j;                 // 24 wave-calls: 3 rows x 8
            int r = cc >> 3, q = cc & 7;
            int yy = y + r - 1;
            if ((unsigned)yy < 128u) {
                int u = (q << 6) + lane;
                int P = (u >> 2) + 1;             // pixel slot 1..128
                int slog = (u & 3) ^ ((P >> 1) & 3);
                const ushort* gp = xT + (size_t)(b * 128 + yy) * rowstride
                                      + (size_t)(P - 1) * Cin + (ck << 5) + (slog << 3);
                short* lp = &sx[(r * 130 + 1) * 32 + (q << 9)];
                gload16(gp, lp);
            }
        }
    };

    const bf16x8* Ab = (const bf16x8*)WbF;
    size_t abase = (size_t)b * NT;

    for (int ck = 0; ck < NC; ck++) {
        stage(ck);
        __syncthreads();                          // drains vmcnt, data visible
        #pragma unroll 3
        for (int rs = 0; rs < 9; rs++) {
            int rr = (rs / 3) * 130;
            int dx = rs % 3 - 1;
            int t = rs * Cdiv32 + ck;
            bf16x8 a[4], bv[4];
            size_t ai = ((abase + t) * 8 + wm * 4) * 64 + lane;
            #pragma unroll
            for (int m = 0; m < 4; m++) a[m] = Ab[ai + (size_t)m * 64];
            int Pb = wn * 64 + (lane & 15) + dx + 1;
            int slog = lane >> 4;
            #pragma unroll
            for (int n = 0; n < 4; n++) {
                int P = Pb + n * 16;
                bv[n] = *(const bf16x8*)&sx[(rr + P) * 32 + ((slog ^ ((P >> 1) & 3)) << 3)];
            }
            #pragma unroll
            for (int m = 0; m < 4; m++)
                #pragma unroll
                for (int n = 0; n < 4; n++)
                    acc[m][n] = __builtin_amdgcn_mfma_f32_16x16x32_bf16(
                        a[m], bv[n], acc[m][n], 0, 0, 0);
        }
        if (ck + 1 < NC) __syncthreads();         // protect buffer before restage
    }

    // epilogue: D row=(lane>>4)*4+r -> out channel, col=lane&15 -> pixel
    int px = wn * 64 + (lane & 15);
    int orow0 = wm * 64 + ((lane >> 4) << 2);
    if (use16) {
        #pragma unroll
        for (int m = 0; m < 4; m++)
            #pragma unroll
            for (int r = 0; r < 4; r++) {
                int oc = orow0 + m * 16 + r;
                ushort* po = out16 + ((size_t)(b * 128 + oc) * 128 + y) * 128 + px;
                #pragma unroll
                for (int n = 0; n < 4; n++) po[n * 16] = f2bf(acc[m][n][r]);
            }
    } else {
        #pragma unroll
        for (int m = 0; m < 4; m++)
            #pragma unroll
            for (int r = 0; r < 4; r++) {
                int oc = orow0 + m * 16 + r;
                float* po = outF + ((size_t)(b * 128 + oc) * 128 + y) * 128 + px;
                #pragma unroll
                for (int n = 0; n < 4; n++) po[n * 16] = acc[m][n][r];
            }
    }

    // fused per-channel partial stats (exact fp32 accumulators)
    #pragma unroll
    for (int m = 0; m < 4; m++)
        #pragma unroll
        for (int r = 0; r < 4; r++) {
            float s = 0.f, q = 0.f;
            #pragma unroll
            for (int n = 0; n < 4; n++) { float v = acc[m][n][r]; s += v; q += v * v; }
            #pragma unroll
            for (int msk = 1; msk < 16; msk <<= 1) {
                s += __shfl_xor(s, msk);
                q += __shfl_xor(q, msk);
            }
            if ((lane & 15) == 0) {
                int chl = m * 16 + ((lane >> 4) << 2) + r;
                sred[wid][chl][0] = s;
                sred[wid][chl][1] = q;
            }
        }
    __syncthreads();
    {
        int ch = tid >> 1, v = tid & 1;
        int wmc = ch >> 6, chl = ch & 63;
        float t2 = sred[wmc * 2][chl][v] + sred[wmc * 2 + 1][chl][v];
        part[((size_t)(b * 128 + y)) * 256 + tid] = t2;
    }
}

// ---------------------------------------------------------------------------
// Reduce per-block partials -> per-channel mean + invstd. grid = 128.
// ---------------------------------------------------------------------------
__global__ void bnred_kernel(const float* __restrict__ part, float* __restrict__ stats,
                             int nrows) {
    int c = blockIdx.x;
    float s = 0.f, q = 0.f;
    for (int by = threadIdx.x; by < nrows; by += blockDim.x) {
        s += part[(size_t)by * 256 + 2 * c];
        q += part[(size_t)by * 256 + 2 * c + 1];
    }
    #pragma unroll
    for (int off = 32; off; off >>= 1) { s += __shfl_down(s, off); q += __shfl_down(q, off); }
    __shared__ float ss[4], qq[4];
    int lane = threadIdx.x & 63, w = threadIdx.x >> 6;
    if (!lane) { ss[w] = s; qq[w] = q; }
    __syncthreads();
    if (!threadIdx.x) {
        s = ss[0] + ss[1] + ss[2] + ss[3];
        q = qq[0] + qq[1] + qq[2] + qq[3];
        const float n = 16.f * 16384.f;
        float m = s / n;
        float var = q / n - m * m;
        stats[2 * c] = m;
        stats[2 * c + 1] = rsqrtf(var + EPS);
    }
}

// ---------------------------------------------------------------------------
// BN apply + ReLU, fp32 NCHW in place.
// ---------------------------------------------------------------------------
__global__ void bnapply_kernel(float4* __restrict__ buf, const float* __restrict__ stats,
                               const float* __restrict__ g, const float* __restrict__ bta,
                               size_t N4) {
    size_t idx = (size_t)blockIdx.x * blockDim.x + threadIdx.x;
    size_t stride = (size_t)gridDim.x * blockDim.x;
    for (; idx < N4; idx += stride) {
        int c = (int)((idx >> 12) & 127);
        float sc = stats[2 * c + 1] * g[c];
        float sh = bta[c] - stats[2 * c] * sc;
        float4 v = buf[idx];
        v.x = fmaxf(v.x * sc + sh, 0.f);
        v.y = fmaxf(v.y * sc + sh, 0.f);
        v.z = fmaxf(v.z * sc + sh, 0.f);
        v.w = fmaxf(v.w * sc + sh, 0.f);
        buf[idx] = v;
    }
}

// ---------------------------------------------------------------------------
// BN apply + ReLU: bf16 NCHW in -> fp32 NCHW out.
// ---------------------------------------------------------------------------
__global__ void bnapply16_kernel(const ushort* __restrict__ in, float4* __restrict__ out,
                                 const float* __restrict__ stats,
                                 const float* __restrict__ g, const float* __restrict__ bta,
                                 size_t N4) {
    size_t idx = (size_t)blockIdx.x * blockDim.x + threadIdx.x;
    size_t stride = (size_t)gridDim.x * blockDim.x;
    for (; idx < N4; idx += stride) {
        int c = (int)((idx >> 12) & 127);
        float sc = stats[2 * c + 1] * g[c];
        float sh = bta[c] - stats[2 * c] * sc;
        ushort4 u = *(const ushort4*)&in[idx * 4];
        float4 v;
        v.x = fmaxf(bf2f(u.x) * sc + sh, 0.f);
        v.y = fmaxf(bf2f(u.y) * sc + sh, 0.f);
        v.z = fmaxf(bf2f(u.z) * sc + sh, 0.f);
        v.w = fmaxf(bf2f(u.w) * sc + sh, 0.f);
        out[idx] = v;
    }
}

// ---------------------------------------------------------------------------
extern "C" void kernel_launch(void* const* d_in, const int* in_sizes, int n_in,
                              void* d_out, int out_size, void* d_ws, size_t ws_size,
                              hipStream_t stream) {
    const int B = 16, Cin1 = 64, C = 128, H = 128, W = 128, HW = H * W;

    const float* x      = (const float*)d_in[0];
    const float* w1     = (const float*)d_in[1];
    const float* a_fc_w = (const float*)d_in[2];
    const float* a_bn_g = (const float*)d_in[3];
    const float* a_bn_b = (const float*)d_in[4];
    const float* a_ch_w = (const float*)d_in[5];
    const float* a_ch_b = (const float*)d_in[6];
    const float* a_fl_w = (const float*)d_in[7];
    const float* a_fl_b = (const float*)d_in[8];
    const float* a_sp_w = (const float*)d_in[9];
    const float* a_sp_b = (const float*)d_in[10];
    const float* a_kn_w = (const float*)d_in[11];
    const float* a_kn_b = (const float*)d_in[12];
    const float* bn1_g  = (const float*)d_in[13];
    const float* bn1_b  = (const float*)d_in[14];
    const float* w2     = (const float*)d_in[15];
    const float* b_fc_w = (const float*)d_in[16];
    const float* b_bn_g = (const float*)d_in[17];
    const float* b_bn_b = (const float*)d_in[18];
    const float* b_ch_w = (const float*)d_in[19];
    const float* b_ch_b = (const float*)d_in[20];
    const float* b_fl_w = (const float*)d_in[21];
    const float* b_fl_b = (const float*)d_in[22];
    const float* b_sp_w = (const float*)d_in[23];
    const float* b_sp_b = (const float*)d_in[24];
    const float* b_kn_w = (const float*)d_in[25];
    const float* b_kn_b = (const float*)d_in[26];
    const float* bn2_g  = (const float*)d_in[27];
    const float* bn2_b  = (const float*)d_in[28];

    float* out = (float*)d_out;
    float* ws  = (float*)d_ws;

    // workspace layout (floats)
    float* XTf   = ws;
    ushort* xT   = (ushort*)XTf;
    float* WBf   = XTf + 16777216;
    ushort* WbF  = (ushort*)WBf;
    float* CPART = WBf + 1179648;
    float* PPART = CPART + 524288;
    float* POOL  = PPART + 1048576;
    float* CH    = POOL + 2048;
    float* FL    = CH + 2048;
    float* SP    = FL + 2048;
    float* KN    = SP + 160;
    float* ST    = KN + 64;
    float* XH2f  = ST + 256;
    ushort* xhat2 = (ushort*)XH2f;

    size_t need = ((size_t)(XH2f - ws) + 16777216) * sizeof(float);
    int fit2 = ws_size >= need;

    ushort* xhat1 = (ushort*)out;                    // d_out as bf16 NCHW scratch

    // ---------------- layer 1 (Cin=64 -> Cout=128) ----------------
    trans_kernel<<<dim3((Cin1 / 32) * 4, H, B), 256, 0, stream>>>(
        x, nullptr, xT, PPART, ST, nullptr, nullptr, Cin1, 0);
    poolred_kernel<<<B * Cin1, 128, 0, stream>>>(PPART, POOL);
    attn_kernel<<<1, 256, 0, stream>>>(POOL, a_fc_w, a_bn_g, a_bn_b, a_ch_w, a_ch_b,
                                       a_fl_w, a_fl_b, a_sp_w, a_sp_b, a_kn_w, a_kn_b,
                                       CH, FL, SP, KN, Cin1, C);
    int NT1 = 9 * Cin1 / 32;
    int N1 = B * NT1 * 4096;
    waggF_kernel<<<(N1 + 255) / 256, 256, 0, stream>>>(w1, CH, FL, SP, KN, WbF, C, Cin1, NT1, N1);
    conv_mfma<<<H * B, 256, 0, stream>>>(xT, WbF, nullptr, xhat1, CPART, Cin1, 1);
    bnred_kernel<<<C, 256, 0, stream>>>(CPART, ST, 2048);
    trans_kernel<<<dim3((C / 32) * 4, H, B), 256, 0, stream>>>(
        nullptr, xhat1, xT, PPART, ST, bn1_g, bn1_b, C, 1);

    // ---------------- layer 2 (Cin=128 -> Cout=128) ----------------
    poolred_kernel<<<B * C, 128, 0, stream>>>(PPART, POOL);
    attn_kernel<<<1, 256, 0, stream>>>(POOL, b_fc_w, b_bn_g, b_bn_b, b_ch_w, b_ch_b,
                                       b_fl_w, b_fl_b, b_sp_w, b_sp_b, b_kn_w, b_kn_b,
                                       CH, FL, SP, KN, C, C);
    int NT2 = 9 * C / 32;
    int N2 = B * NT2 * 4096;
    waggF_kernel<<<(N2 + 255) / 256, 256, 0, stream>>>(w2, CH, FL, SP, KN, WbF, C, C, NT2, N2);
    if (fit2) {
        conv_mfma<<<H * B, 256, 0, stream>>>(xT, WbF, nullptr, xhat2, CPART, C, 1);
        bnred_kernel<<<C, 256, 0, stream>>>(CPART, ST, 2048);
        bnapply16_kernel<<<2048, 256, 0, stream>>>(xhat2, (float4*)out, ST, bn2_g, bn2_b,
                                                   (size_t)B * C * HW / 4);
    } else {
        conv_mfma<<<H * B, 256, 0, stream>>>(xT, WbF, out, nullptr, CPART, C, 0);
        bnred_kernel<<<C, 256, 0, stream>>>(CPART, ST, 2048);
        bnapply_kernel<<<2048, 256, 0, stream>>>((float4*)out, ST, bn2_g, bn2_b,
                                                 (size_t)B * C * HW / 4);
    }
}

// Round 12
// 307.821 us; speedup vs baseline: 4.8530x; 1.1584x over previous
//
#include <hip/hip_runtime.h>
#include <hip/hip_bf16.h>
#include <math.h>

#define EPS 1e-5f

typedef __attribute__((ext_vector_type(8))) short bf16x8;
typedef __attribute__((ext_vector_type(4))) float f32x4;

__device__ inline ushort f2bf(float f) {
    uint u = __float_as_uint(f);
    uint r = (u + 0x7fffu + ((u >> 16) & 1u)) >> 16;
    return (ushort)r;
}
__device__ inline float bf2f(ushort u) {
    return __uint_as_float(((uint)u) << 16);
}
__device__ inline float sigmoidf_(float x) { return 1.f / (1.f + expf(-x)); }

__device__ inline void gload16(const void* g, void* l) {
    __builtin_amdgcn_global_load_lds((const __attribute__((address_space(1))) unsigned int*)g,
                                     (__attribute__((address_space(3))) unsigned int*)l,
                                     16, 0, 0);
}

// ---------------------------------------------------------------------------
// Attention head (single block, 256 threads). B=16, A=16, K=4 fixed.
// ---------------------------------------------------------------------------
__global__ void attn_kernel(const float* __restrict__ pooled,
                            const float* __restrict__ fc_w,
                            const float* __restrict__ bn_g, const float* __restrict__ bn_b,
                            const float* __restrict__ ch_w, const float* __restrict__ ch_b,
                            const float* __restrict__ fl_w, const float* __restrict__ fl_b,
                            const float* __restrict__ sp_w, const float* __restrict__ sp_b,
                            const float* __restrict__ kn_w, const float* __restrict__ kn_b,
                            float* __restrict__ ch_att, float* __restrict__ fl_att,
                            float* __restrict__ sp_att, float* __restrict__ kn_att,
                            int C, int Cout) {
    const int Bb = 16, A = 16, K = 4;
    __shared__ float h[16][16];
    int tid = threadIdx.x;

    if (tid < Bb * A) {
        int b = tid >> 4, a = tid & 15;
        const float* pr = pooled + b * C;
        const float* fw = fc_w + a * C;
        float s = 0.f;
        for (int c = 0; c < C; c++) s += pr[c] * fw[c];
        h[b][a] = s;
    }
    __syncthreads();

    if (tid < A) {
        int a = tid;
        float m = 0.f;
        for (int b = 0; b < Bb; b++) m += h[b][a];
        m *= (1.f / 16.f);
        float v = 0.f;
        for (int b = 0; b < Bb; b++) { float d = h[b][a] - m; v += d * d; }
        v *= (1.f / 16.f);
        float inv = rsqrtf(v + EPS);
        float g = bn_g[a], bb = bn_b[a];
        for (int b = 0; b < Bb; b++) {
            float t = (h[b][a] - m) * inv * g + bb;
            h[b][a] = t > 0.f ? t : 0.f;
        }
    }
    __syncthreads();

    for (int idx = tid; idx < Bb * C; idx += blockDim.x) {
        int b = idx / C, c = idx % C;
        float s = ch_b[c];
        #pragma unroll
        for (int a = 0; a < A; a++) s += h[b][a] * ch_w[c * A + a];
        ch_att[idx] = sigmoidf_(s);
    }
    for (int idx = tid; idx < Bb * Cout; idx += blockDim.x) {
        int b = idx / Cout, o = idx % Cout;
        float s = fl_b[o];
        #pragma unroll
        for (int a = 0; a < A; a++) s += h[b][a] * fl_w[o * A + a];
        fl_att[idx] = sigmoidf_(s);
    }
    for (int idx = tid; idx < Bb * 9; idx += blockDim.x) {
        int b = idx / 9, r = idx % 9;
        float s = sp_b[r];
        #pragma unroll
        for (int a = 0; a < A; a++) s += h[b][a] * sp_w[r * A + a];
        sp_att[idx] = sigmoidf_(s);
    }
    if (tid < Bb) {
        int b = tid;
        float l[K], mx = -1e30f;
        #pragma unroll
        for (int k = 0; k < K; k++) {
            float s = kn_b[k];
            #pragma unroll
            for (int a = 0; a < A; a++) s += h[b][a] * kn_w[k * A + a];
            l[k] = s; mx = fmaxf(mx, s);
        }
        float den = 0.f;
        #pragma unroll
        for (int k = 0; k < K; k++) { l[k] = expf(l[k] - mx); den += l[k]; }
        #pragma unroll
        for (int k = 0; k < K; k++) kn_att[b * K + k] = l[k] / den;
    }
}

// ---------------------------------------------------------------------------
// Effective weight aggregation -> bf16 in 16x16x32 MFMA A-fragment order.
// ---------------------------------------------------------------------------
__global__ void waggF_kernel(const float* __restrict__ W4, const float* __restrict__ ch,
                             const float* __restrict__ fl, const float* __restrict__ sp,
                             const float* __restrict__ kn, ushort* __restrict__ WbF,
                             int Cout, int Cin, int NT, int N) {
    int idx = blockIdx.x * blockDim.x + threadIdx.x;
    if (idx >= N) return;
    int e = idx & 7;
    int l = (idx >> 3) & 63;
    int ot = (idx >> 9) & 7;
    int tb = idx >> 12;
    int t = tb % NT, b = tb / NT;
    int o = ot * 16 + (l & 15);
    int k = t * 32 + ((l >> 4) << 3) + e;
    int rs = k / Cin, i = k - rs * Cin;
    size_t kstride = (size_t)Cout * Cin * 9;
    const float* wp = W4 + ((size_t)o * Cin + i) * 9 + rs;
    const float* kp = kn + b * 4;
    float s = kp[0] * wp[0] + kp[1] * wp[kstride] + kp[2] * wp[2 * kstride] + kp[3] * wp[3 * kstride];
    float v = fl[b * Cout + o] * ch[b * Cin + i] * sp[b * 9 + rs] * s;
    WbF[idx] = f2bf(v);
}

// ---------------------------------------------------------------------------
// NCHW (fp32 OR bf16) -> NHWC bf16 tiled transpose, optional BN+ReLU, fused
// global-avg-pool partials. grid ((C/32)*(W/32), H, B), block 256.
// Vectorized: 16B/lane fp32 loads (4 px), 8B/lane bf16 loads, 8B/lane stores.
// ---------------------------------------------------------------------------
__global__ __launch_bounds__(256) void trans_kernel(const float* __restrict__ in32,
                                                    const ushort* __restrict__ in16,
                                                    ushort* __restrict__ out,
                                                    float* __restrict__ ppart,
                                                    const float* __restrict__ stats,
                                                    const float* __restrict__ g,
                                                    const float* __restrict__ beta,
                                                    int C, int doBN) {
    int tilesC = C >> 5;
    int cbi = blockIdx.x % tilesC;
    int pbi = blockIdx.x / tilesC;
    int cb = cbi << 5, pb = pbi << 5;
    int y = blockIdx.y, b = blockIdx.z;
    __shared__ float tile[32][33];
    int t = threadIdx.x;
    int c0 = t >> 3, p4 = t & 7;                  // lane owns 4 px of channel c0
    int c = cb + c0;
    size_t base = (((size_t)b * C + c) * 128 + y) * 128 + pb + p4 * 4;
    float v0, v1, v2, v3;
    if (in16) {
        ushort4 u = *(const ushort4*)&in16[base];
        v0 = bf2f(u.x); v1 = bf2f(u.y); v2 = bf2f(u.z); v3 = bf2f(u.w);
    } else {
        float4 f = *(const float4*)&in32[base];
        v0 = f.x; v1 = f.y; v2 = f.z; v3 = f.w;
    }
    if (doBN) {
        float sc = stats[2 * c + 1] * g[c];
        float sh = beta[c] - stats[2 * c] * sc;
        v0 = fmaxf(v0 * sc + sh, 0.f);
        v1 = fmaxf(v1 * sc + sh, 0.f);
        v2 = fmaxf(v2 * sc + sh, 0.f);
        v3 = fmaxf(v3 * sc + sh, 0.f);
    }
    tile[c0][p4 * 4 + 0] = v0;
    tile[c0][p4 * 4 + 1] = v1;
    tile[c0][p4 * 4 + 2] = v2;
    tile[c0][p4 * 4 + 3] = v3;
    // pool partial: sum over the 32 px (8 lanes x 4 each); lanes of one c0 are
    // the 8-aligned group t = c0*8 .. c0*8+7 -> xor masks 1,2,4 stay in group
    {
        float s = v0 + v1 + v2 + v3;
        s += __shfl_xor(s, 1);
        s += __shfl_xor(s, 2);
        s += __shfl_xor(s, 4);
        if (p4 == 0)
            ppart[((size_t)((b * tilesC + cbi) * 32 + c0)) * 512 + pbi * 128 + y] = s;
    }
    __syncthreads();
    // store: lane handles (px = t>>3, 4 channels at (t&7)*4), 8B per lane
    {
        int p = t >> 3, c4 = (t & 7) << 2;
        uint lo = (uint)f2bf(tile[c4][p]) | ((uint)f2bf(tile[c4 + 1][p]) << 16);
        uint hi = (uint)f2bf(tile[c4 + 2][p]) | ((uint)f2bf(tile[c4 + 3][p]) << 16);
        uint2 w = {lo, hi};
        *(uint2*)&out[(((size_t)b * 128 + y) * 128 + pb + p) * C + cb + c4] = w;
    }
}

// ---------------------------------------------------------------------------
// Reduce pool partials. grid=B*C.
// ---------------------------------------------------------------------------
__global__ void poolred_kernel(const float* __restrict__ part, float* __restrict__ pool) {
    int bc = blockIdx.x;
    const float* p = part + (size_t)bc * 512;
    float s = 0.f;
    for (int i = threadIdx.x; i < 512; i += 128) s += p[i];
    #pragma unroll
    for (int off = 32; off; off >>= 1) s += __shfl_down(s, off);
    __shared__ float tmp[2];
    if ((threadIdx.x & 63) == 0) tmp[threadIdx.x >> 6] = s;
    __syncthreads();
    if (!threadIdx.x) pool[bc] = (tmp[0] + tmp[1]) * (1.f / 16384.f);
}

// ---------------------------------------------------------------------------
// Implicit-GEMM conv 3x3 pad 1 via MFMA 16x16x32. Single-buffer LDS (~27 KB),
// __launch_bounds__(256,4). 4 blocks/CU inter-block overlap. Grid 2048 with
// XCD swizzle. 32-ch chunks via global_load_lds, source-side XOR swizzle.
// Fused BN partial stats. Output bf16 or fp32 NCHW.  [UNCHANGED from R11]
// ---------------------------------------------------------------------------
__global__ __launch_bounds__(256, 4) void conv_mfma(const ushort* __restrict__ xT,
                                                    const ushort* __restrict__ WbF,
                                                    float* __restrict__ outF,
                                                    ushort* __restrict__ out16,
                                                    float* __restrict__ part,
                                                    int Cin, int use16) {
    const int BUFSH = 3 * 130 * 32;              // 12,480 shorts = 24,960 B
    __shared__ short sx[BUFSH];
    __shared__ float sred[4][64][2];
    int id = blockIdx.x;
    int swz = (id & 7) * (gridDim.x >> 3) + (id >> 3);
    int y = swz & 127, b = swz >> 7;
    int tid = threadIdx.x;
    int lane = tid & 63, wid = tid >> 6;
    int wm = wid >> 1, wn = wid & 1;
    int Cdiv32 = Cin >> 5;
    int NC = Cdiv32;
    int NT = 9 * Cdiv32;

    f32x4 acc[4][4] = {};

    {
        bf16x8 z = {};
        for (int e = tid * 8; e < BUFSH; e += 2048) *(bf16x8*)&sx[e] = z;
    }
    __syncthreads();

    const size_t rowstride = (size_t)128 * Cin;

    auto stage = [&](int ck) {
        #pragma unroll
        for (int j = 0; j < 6; j++) {
            int cc = wid + 4 * j;
            int r = cc >> 3, q = cc & 7;
            int yy = y + r - 1;
            if ((unsigned)yy < 128u) {
                int u = (q << 6) + lane;
                int P = (u >> 2) + 1;
                int slog = (u & 3) ^ ((P >> 1) & 3);
                const ushort* gp = xT + (size_t)(b * 128 + yy) * rowstride
                                      + (size_t)(P - 1) * Cin + (ck << 5) + (slog << 3);
                short* lp = &sx[(r * 130 + 1) * 32 + (q << 9)];
                gload16(gp, lp);
            }
        }
    };

    const bf16x8* Ab = (const bf16x8*)WbF;
    size_t abase = (size_t)b * NT;

    for (int ck = 0; ck < NC; ck++) {
        stage(ck);
        __syncthreads();
        #pragma unroll 3
        for (int rs = 0; rs < 9; rs++) {
            int rr = (rs / 3) * 130;
            int dx = rs % 3 - 1;
            int t = rs * Cdiv32 + ck;
            bf16x8 a[4], bv[4];
            size_t ai = ((abase + t) * 8 + wm * 4) * 64 + lane;
            #pragma unroll
            for (int m = 0; m < 4; m++) a[m] = Ab[ai + (size_t)m * 64];
            int Pb = wn * 64 + (lane & 15) + dx + 1;
            int slog = lane >> 4;
            #pragma unroll
            for (int n = 0; n < 4; n++) {
                int P = Pb + n * 16;
                bv[n] = *(const bf16x8*)&sx[(rr + P) * 32 + ((slog ^ ((P >> 1) & 3)) << 3)];
            }
            #pragma unroll
            for (int m = 0; m < 4; m++)
                #pragma unroll
                for (int n = 0; n < 4; n++)
                    acc[m][n] = __builtin_amdgcn_mfma_f32_16x16x32_bf16(
                        a[m], bv[n], acc[m][n], 0, 0, 0);
        }
        if (ck + 1 < NC) __syncthreads();
    }

    int px = wn * 64 + (lane & 15);
    int orow0 = wm * 64 + ((lane >> 4) << 2);
    if (use16) {
        #pragma unroll
        for (int m = 0; m < 4; m++)
            #pragma unroll
            for (int r = 0; r < 4; r++) {
                int oc = orow0 + m * 16 + r;
                ushort* po = out16 + ((size_t)(b * 128 + oc) * 128 + y) * 128 + px;
                #pragma unroll
                for (int n = 0; n < 4; n++) po[n * 16] = f2bf(acc[m][n][r]);
            }
    } else {
        #pragma unroll
        for (int m = 0; m < 4; m++)
            #pragma unroll
            for (int r = 0; r < 4; r++) {
                int oc = orow0 + m * 16 + r;
                float* po = outF + ((size_t)(b * 128 + oc) * 128 + y) * 128 + px;
                #pragma unroll
                for (int n = 0; n < 4; n++) po[n * 16] = acc[m][n][r];
            }
    }

    #pragma unroll
    for (int m = 0; m < 4; m++)
        #pragma unroll
        for (int r = 0; r < 4; r++) {
            float s = 0.f, q = 0.f;
            #pragma unroll
            for (int n = 0; n < 4; n++) { float v = acc[m][n][r]; s += v; q += v * v; }
            #pragma unroll
            for (int msk = 1; msk < 16; msk <<= 1) {
                s += __shfl_xor(s, msk);
                q += __shfl_xor(q, msk);
            }
            if ((lane & 15) == 0) {
                int chl = m * 16 + ((lane >> 4) << 2) + r;
                sred[wid][chl][0] = s;
                sred[wid][chl][1] = q;
            }
        }
    __syncthreads();
    {
        int ch = tid >> 1, v = tid & 1;
        int wmc = ch >> 6, chl = ch & 63;
        float t2 = sred[wmc * 2][chl][v] + sred[wmc * 2 + 1][chl][v];
        part[((size_t)(b * 128 + y)) * 256 + tid] = t2;
    }
}

// ---------------------------------------------------------------------------
// Reduce per-block partials -> per-channel mean + invstd. grid = 128.
// ---------------------------------------------------------------------------
__global__ void bnred_kernel(const float* __restrict__ part, float* __restrict__ stats,
                             int nrows) {
    int c = blockIdx.x;
    float s = 0.f, q = 0.f;
    for (int by = threadIdx.x; by < nrows; by += blockDim.x) {
        s += part[(size_t)by * 256 + 2 * c];
        q += part[(size_t)by * 256 + 2 * c + 1];
    }
    #pragma unroll
    for (int off = 32; off; off >>= 1) { s += __shfl_down(s, off); q += __shfl_down(q, off); }
    __shared__ float ss[4], qq[4];
    int lane = threadIdx.x & 63, w = threadIdx.x >> 6;
    if (!lane) { ss[w] = s; qq[w] = q; }
    __syncthreads();
    if (!threadIdx.x) {
        s = ss[0] + ss[1] + ss[2] + ss[3];
        q = qq[0] + qq[1] + qq[2] + qq[3];
        const float n = 16.f * 16384.f;
        float m = s / n;
        float var = q / n - m * m;
        stats[2 * c] = m;
        stats[2 * c + 1] = rsqrtf(var + EPS);
    }
}

// ---------------------------------------------------------------------------
// BN apply + ReLU, fp32 NCHW in place.
// ---------------------------------------------------------------------------
__global__ void bnapply_kernel(float4* __restrict__ buf, const float* __restrict__ stats,
                               const float* __restrict__ g, const float* __restrict__ bta,
                               size_t N4) {
    size_t idx = (size_t)blockIdx.x * blockDim.x + threadIdx.x;
    size_t stride = (size_t)gridDim.x * blockDim.x;
    for (; idx < N4; idx += stride) {
        int c = (int)((idx >> 12) & 127);
        float sc = stats[2 * c + 1] * g[c];
        float sh = bta[c] - stats[2 * c] * sc;
        float4 v = buf[idx];
        v.x = fmaxf(v.x * sc + sh, 0.f);
        v.y = fmaxf(v.y * sc + sh, 0.f);
        v.z = fmaxf(v.z * sc + sh, 0.f);
        v.w = fmaxf(v.w * sc + sh, 0.f);
        buf[idx] = v;
    }
}

// ---------------------------------------------------------------------------
// BN apply + ReLU: bf16 NCHW in -> fp32 NCHW out. 16B/lane reads, 32B writes.
// idx unit = 8 px; c = (idx >> 11) & 127 (HW = 16384).
// ---------------------------------------------------------------------------
__global__ void bnapply16_kernel(const ushort* __restrict__ in, float4* __restrict__ out,
                                 const float* __restrict__ stats,
                                 const float* __restrict__ g, const float* __restrict__ bta,
                                 size_t N8) {
    size_t idx = (size_t)blockIdx.x * blockDim.x + threadIdx.x;
    size_t stride = (size_t)gridDim.x * blockDim.x;
    for (; idx < N8; idx += stride) {
        int c = (int)((idx >> 11) & 127);
        float sc = stats[2 * c + 1] * g[c];
        float sh = bta[c] - stats[2 * c] * sc;
        bf16x8 u = *(const bf16x8*)&in[idx * 8];
        float4 v0, v1;
        v0.x = fmaxf(bf2f((ushort)u[0]) * sc + sh, 0.f);
        v0.y = fmaxf(bf2f((ushort)u[1]) * sc + sh, 0.f);
        v0.z = fmaxf(bf2f((ushort)u[2]) * sc + sh, 0.f);
        v0.w = fmaxf(bf2f((ushort)u[3]) * sc + sh, 0.f);
        v1.x = fmaxf(bf2f((ushort)u[4]) * sc + sh, 0.f);
        v1.y = fmaxf(bf2f((ushort)u[5]) * sc + sh, 0.f);
        v1.z = fmaxf(bf2f((ushort)u[6]) * sc + sh, 0.f);
        v1.w = fmaxf(bf2f((ushort)u[7]) * sc + sh, 0.f);
        out[idx * 2] = v0;
        out[idx * 2 + 1] = v1;
    }
}

// ---------------------------------------------------------------------------
extern "C" void kernel_launch(void* const* d_in, const int* in_sizes, int n_in,
                              void* d_out, int out_size, void* d_ws, size_t ws_size,
                              hipStream_t stream) {
    const int B = 16, Cin1 = 64, C = 128, H = 128, W = 128, HW = H * W;

    const float* x      = (const float*)d_in[0];
    const float* w1     = (const float*)d_in[1];
    const float* a_fc_w = (const float*)d_in[2];
    const float* a_bn_g = (const float*)d_in[3];
    const float* a_bn_b = (const float*)d_in[4];
    const float* a_ch_w = (const float*)d_in[5];
    const float* a_ch_b = (const float*)d_in[6];
    const float* a_fl_w = (const float*)d_in[7];
    const float* a_fl_b = (const float*)d_in[8];
    const float* a_sp_w = (const float*)d_in[9];
    const float* a_sp_b = (const float*)d_in[10];
    const float* a_kn_w = (const float*)d_in[11];
    const float* a_kn_b = (const float*)d_in[12];
    const float* bn1_g  = (const float*)d_in[13];
    const float* bn1_b  = (const float*)d_in[14];
    const float* w2     = (const float*)d_in[15];
    const float* b_fc_w = (const float*)d_in[16];
    const float* b_bn_g = (const float*)d_in[17];
    const float* b_bn_b = (const float*)d_in[18];
    const float* b_ch_w = (const float*)d_in[19];
    const float* b_ch_b = (const float*)d_in[20];
    const float* b_fl_w = (const float*)d_in[21];
    const float* b_fl_b = (const float*)d_in[22];
    const float* b_sp_w = (const float*)d_in[23];
    const float* b_sp_b = (const float*)d_in[24];
    const float* b_kn_w = (const float*)d_in[25];
    const float* b_kn_b = (const float*)d_in[26];
    const float* bn2_g  = (const float*)d_in[27];
    const float* bn2_b  = (const float*)d_in[28];

    float* out = (float*)d_out;
    float* ws  = (float*)d_ws;

    // workspace layout (floats)
    float* XTf   = ws;
    ushort* xT   = (ushort*)XTf;
    float* WBf   = XTf + 16777216;
    ushort* WbF  = (ushort*)WBf;
    float* CPART = WBf + 1179648;
    float* PPART = CPART + 524288;
    float* POOL  = PPART + 1048576;
    float* CH    = POOL + 2048;
    float* FL    = CH + 2048;
    float* SP    = FL + 2048;
    float* KN    = SP + 160;
    float* ST    = KN + 64;
    float* XH2f  = ST + 256;
    ushort* xhat2 = (ushort*)XH2f;

    size_t need = ((size_t)(XH2f - ws) + 16777216) * sizeof(float);
    int fit2 = ws_size >= need;

    ushort* xhat1 = (ushort*)out;                    // d_out as bf16 NCHW scratch

    // ---------------- layer 1 (Cin=64 -> Cout=128) ----------------
    trans_kernel<<<dim3((Cin1 / 32) * 4, H, B), 256, 0, stream>>>(
        x, nullptr, xT, PPART, ST, nullptr, nullptr, Cin1, 0);
    poolred_kernel<<<B * Cin1, 128, 0, stream>>>(PPART, POOL);
    attn_kernel<<<1, 256, 0, stream>>>(POOL, a_fc_w, a_bn_g, a_bn_b, a_ch_w, a_ch_b,
                                       a_fl_w, a_fl_b, a_sp_w, a_sp_b, a_kn_w, a_kn_b,
                                       CH, FL, SP, KN, Cin1, C);
    int NT1 = 9 * Cin1 / 32;
    int N1 = B * NT1 * 4096;
    waggF_kernel<<<(N1 + 255) / 256, 256, 0, stream>>>(w1, CH, FL, SP, KN, WbF, C, Cin1, NT1, N1);
    conv_mfma<<<H * B, 256, 0, stream>>>(xT, WbF, nullptr, xhat1, CPART, Cin1, 1);
    bnred_kernel<<<C, 256, 0, stream>>>(CPART, ST, 2048);
    trans_kernel<<<dim3((C / 32) * 4, H, B), 256, 0, stream>>>(
        nullptr, xhat1, xT, PPART, ST, bn1_g, bn1_b, C, 1);

    // ---------------- layer 2 (Cin=128 -> Cout=128) ----------------
    poolred_kernel<<<B * C, 128, 0, stream>>>(PPART, POOL);
    attn_kernel<<<1, 256, 0, stream>>>(POOL, b_fc_w, b_bn_g, b_bn_b, b_ch_w, b_ch_b,
                                       b_fl_w, b_fl_b, b_sp_w, b_sp_b, b_kn_w, b_kn_b,
                                       CH, FL, SP, KN, C, C);
    int NT2 = 9 * C / 32;
    int N2 = B * NT2 * 4096;
    waggF_kernel<<<(N2 + 255) / 256, 256, 0, stream>>>(w2, CH, FL, SP, KN, WbF, C, C, NT2, N2);
    if (fit2) {
        conv_mfma<<<H * B, 256, 0, stream>>>(xT, WbF, nullptr, xhat2, CPART, C, 1);
        bnred_kernel<<<C, 256, 0, stream>>>(CPART, ST, 2048);
        bnapply16_kernel<<<2048, 256, 0, stream>>>(xhat2, (float4*)out, ST, bn2_g, bn2_b,
                                                   (size_t)B * C * HW / 8);
    } else {
        conv_mfma<<<H * B, 256, 0, stream>>>(xT, WbF, out, nullptr, CPART, C, 0);
        bnred_kernel<<<C, 256, 0, stream>>>(CPART, ST, 2048);
        bnapply_kernel<<<2048, 256, 0, stream>>>((float4*)out, ST, bn2_g, bn2_b,
                                                 (size_t)B * C * HW / 4);
    }
}